// Round 6
// baseline (1463.341 us; speedup 1.0000x reference)
//
#include <hip/hip_runtime.h>
#include <stdint.h>

#define TOKENS 8192
#define IN_F   4096
#define OUT_F  16384

#define BM 256
#define BN 256
#define BK 128                 // i8: 128 bytes per row
#define NT (IN_F / BK)         // 32 K-tiles

typedef __attribute__((ext_vector_type(4))) float f32x4;
typedef __attribute__((ext_vector_type(4))) int i32x4;

// ---------------- conversion kernels ----------------

__device__ __forceinline__ int pack4(int a, int b, int c, int d) {
  return (a & 0xff) | ((b & 0xff) << 8) | ((c & 0xff) << 16) | ((d & 0xff) << 24);
}

// w int32 {-1,0,1} -> i8, 16 elems/thread
__global__ void convert_w_i8(const int* __restrict__ w,
                             int8_t* __restrict__ wq, int n16) {
  int stride = gridDim.x * blockDim.x;
  for (int i = blockIdx.x * blockDim.x + threadIdx.x; i < n16; i += stride) {
    i32x4 o;
#pragma unroll
    for (int j = 0; j < 4; ++j) {
      i32x4 a = ((const i32x4*)w)[(size_t)i * 4 + j];
      o[j] = pack4(a.x, a.y, a.z, a.w);
    }
    ((i32x4*)wq)[i] = o;
  }
}

// x f32 -> per-token-scaled i8; one block per token (256 thr, 16 elems/thr)
__global__ void convert_x_i8(const float* __restrict__ x,
                             int8_t* __restrict__ xq,
                             float* __restrict__ xs) {
  const int t = blockIdx.x;
  const int tid = threadIdx.x;
  const float* xr = x + (size_t)t * IN_F;

  f32x4 v[4];
  float m = 0.f;
#pragma unroll
  for (int i = 0; i < 4; ++i) {
    v[i] = ((const f32x4*)xr)[tid * 4 + i];
    m = fmaxf(m, fmaxf(fmaxf(fabsf(v[i].x), fabsf(v[i].y)),
                       fmaxf(fabsf(v[i].z), fabsf(v[i].w))));
  }
#pragma unroll
  for (int off = 32; off; off >>= 1) m = fmaxf(m, __shfl_xor(m, off));
  __shared__ float sm[4];
  if ((tid & 63) == 0) sm[tid >> 6] = m;
  __syncthreads();
  m = fmaxf(fmaxf(sm[0], sm[1]), fmaxf(sm[2], sm[3]));

  const float inv = (m > 0.f) ? (127.f / m) : 0.f;
  if (tid == 0) xs[t] = m / 127.f;

  i32x4 o;
#pragma unroll
  for (int i = 0; i < 4; ++i) {
    o[i] = pack4(__float2int_rn(v[i].x * inv), __float2int_rn(v[i].y * inv),
                 __float2int_rn(v[i].z * inv), __float2int_rn(v[i].w * inv));
  }
  ((i32x4*)(xq + (size_t)t * IN_F))[tid] = o;
}

// ---------------- 256x256 8-phase i8 GEMM (16x16x64 MFMA) ----------------
// A: [TOKENS][IN_F] i8 (per-token scaled), B: [OUT_F][IN_F] i8 ternary (NT GEMM).
// C[t][o] = (sum_k Aq[t][k]*Wq[o][k]) * xs[t]*wscale + bias[o].
// R6: B-frags register-double-buffered via straight-line 2-tile macro unroll
//     (R5's lambda-by-reference put the arrays in scratch). Reads 4/4/8/8.

__device__ __forceinline__ void async_lds_16B(const int8_t* g, int8_t* l) {
  __builtin_amdgcn_global_load_lds(
      reinterpret_cast<const __attribute__((address_space(1))) unsigned int*>(
          reinterpret_cast<uintptr_t>(g)),
      reinterpret_cast<__attribute__((address_space(3))) unsigned int*>(
          reinterpret_cast<uintptr_t>(l)),
      16, 0, 0);
}

__global__ __launch_bounds__(512, 2)
void ternary_gemm_i8(const int8_t* __restrict__ A,
                     const int8_t* __restrict__ B,
                     const float* __restrict__ xs,
                     const float* __restrict__ scale_p,
                     const float* __restrict__ bias,
                     float* __restrict__ C) {
  // [dbuf][A=0/B=1][256 rows * 128 B] = 128 KiB
  __shared__ __attribute__((aligned(16))) int8_t lds[2][2][BM * BK];

  const int nbn = OUT_F / BN;       // 64
  const int cpx = gridDim.x >> 3;   // 2048/8 = 256 (bijective)
  const int bid = blockIdx.x;
  const int swz = (bid & 7) * cpx + (bid >> 3);
  const int bm = swz / nbn;
  const int bn = swz % nbn;

  const int tid  = threadIdx.x;
  const int lane = tid & 63;
  const int wid  = tid >> 6;   // 0..7
  const int wr   = wid >> 2;   // 0..1 (M)
  const int wc   = wid & 3;    // 0..3 (N)

  const int r = lane & 15;          // frag row/col within 16
  const int g = lane >> 4;          // k-group 0..3
  const int swzr = (r & 7) * 16;    // read-side XOR swizzle (bytes)

  const int8_t* Ag = A + (size_t)bm * BM * IN_F;
  const int8_t* Bg = B + (size_t)bn * BN * IN_F;

  // staging: linear LDS dest (wave-uniform base + lane*16), inverse-swizzled src
  const int s_rowoff = lane >> 3;                         // 0..7
  const int s_colb   = ((lane & 7) ^ (lane >> 3)) * 16;   // pre-swizzled byte col

  auto stage = [&](int8_t* ldsTile, const int8_t* gTile, int half, int kt) {
#pragma unroll
    for (int i = 0; i < 2; ++i) {
      const int rbase = half * 128 + wid * 16 + i * 8;    // wave-uniform
      const int8_t* src =
          gTile + (size_t)(rbase + s_rowoff) * IN_F + kt * BK + s_colb;
      async_lds_16B(src, ldsTile + rbase * BK);
    }
  };

  i32x4 acc[8][4];
#pragma unroll
  for (int m = 0; m < 8; ++m)
#pragma unroll
    for (int n = 0; n < 4; ++n) acc[m][n] = i32x4{0, 0, 0, 0};

  // ---- prologue: tile0 {B0,B1,A0,A1} + tile1 {B0,B1,A0}; drain tile0 ----
  stage(&lds[0][1][0], Bg, 0, 0);
  stage(&lds[0][1][0], Bg, 1, 0);
  stage(&lds[0][0][0], Ag, 0, 0);
  stage(&lds[0][0][0], Ag, 1, 0);
  stage(&lds[1][1][0], Bg, 0, 1);
  stage(&lds[1][1][0], Bg, 1, 1);
  stage(&lds[1][0][0], Ag, 0, 1);
  asm volatile("s_waitcnt vmcnt(6)" ::: "memory");
  __builtin_amdgcn_s_barrier();

  i32x4 bfrA[4][2], bfrB[4][2];
  // pre-read tile0's B fragments (drained by t0-ph0's lgkmcnt(0))
#pragma unroll
  for (int n = 0; n < 4; ++n)
#pragma unroll
    for (int ks = 0; ks < 2; ++ks)
      bfrA[n][ks] = *(const i32x4*)(&lds[0][1][0] +
                                    (wc * 64 + n * 16 + r) * BK +
                                    ((ks * 64 + g * 16) ^ swzr));

// One K-tile body. CUR = compile-time buffer parity; BFR = this tile's B frags
// (already in regs); BFN = next tile's B frags (filled in phase 3).
#define TILE_BODY(T, CUR, BFR, BFN)                                            \
  {                                                                            \
    const int t_ = (T);                                                        \
    const int8_t* Ab = &lds[(CUR)][0][0];                                      \
    int8_t* Abw = &lds[(CUR)][0][0];                                           \
    int8_t* Bbw = &lds[(CUR)][1][0];                                           \
    int8_t* An  = &lds[(CUR) ^ 1][0][0];                                       \
    const int8_t* BbN = &lds[(CUR) ^ 1][1][0];                                 \
    /* phase 0: read A-quad0 (4); stage (t+1).A1 */                            \
    i32x4 a0[2][2];                                                            \
    _Pragma("unroll") for (int m = 0; m < 2; ++m)                              \
        _Pragma("unroll") for (int ks = 0; ks < 2; ++ks)                       \
            a0[m][ks] = *(const i32x4*)(Ab + (wr * 128 + m * 16 + r) * BK +    \
                                        ((ks * 64 + g * 16) ^ swzr));          \
    if (t_ + 1 < NT) stage(An, Ag, 1, t_ + 1);                                 \
    __builtin_amdgcn_s_barrier();                                              \
    asm volatile("s_waitcnt lgkmcnt(0)" ::: "memory");                         \
    __builtin_amdgcn_s_setprio(1);                                             \
    _Pragma("unroll") for (int ks = 0; ks < 2; ++ks)                           \
        _Pragma("unroll") for (int m = 0; m < 2; ++m)                          \
            _Pragma("unroll") for (int n = 0; n < 4; ++n)                      \
                acc[m][n] = __builtin_amdgcn_mfma_i32_16x16x64_i8(             \
                    a0[m][ks], BFR[n][ks], acc[m][n], 0, 0, 0);                \
    __builtin_amdgcn_s_setprio(0);                                             \
    __builtin_amdgcn_s_barrier();                                              \
    /* phase 1: read A-quad1 (4); stage (t+2).B0 in-place */                   \
    i32x4 a1[2][2];                                                            \
    _Pragma("unroll") for (int m = 0; m < 2; ++m)                              \
        _Pragma("unroll") for (int ks = 0; ks < 2; ++ks)                       \
            a1[m][ks] = *(const i32x4*)(Ab +                                   \
                                        (wr * 128 + (2 + m) * 16 + r) * BK +   \
                                        ((ks * 64 + g * 16) ^ swzr));          \
    if (t_ + 2 < NT) stage(Bbw, Bg, 0, t_ + 2);                                \
    __builtin_amdgcn_s_barrier();                                              \
    asm volatile("s_waitcnt lgkmcnt(0)" ::: "memory");                         \
    __builtin_amdgcn_s_setprio(1);                                             \
    _Pragma("unroll") for (int ks = 0; ks < 2; ++ks)                           \
        _Pragma("unroll") for (int m = 0; m < 2; ++m)                          \
            _Pragma("unroll") for (int n = 0; n < 4; ++n)                      \
                acc[2 + m][n] = __builtin_amdgcn_mfma_i32_16x16x64_i8(         \
                    a1[m][ks], BFR[n][ks], acc[2 + m][n], 0, 0, 0);            \
    __builtin_amdgcn_s_setprio(0);                                             \
    __builtin_amdgcn_s_barrier();                                              \
    /* phase 2: read A-quad2+quad3 (8); stage (t+2).B1 in-place */             \
    i32x4 a2[2][2], a3[2][2];                                                  \
    _Pragma("unroll") for (int m = 0; m < 2; ++m)                              \
        _Pragma("unroll") for (int ks = 0; ks < 2; ++ks) {                     \
      a2[m][ks] = *(const i32x4*)(Ab + (wr * 128 + (4 + m) * 16 + r) * BK +    \
                                  ((ks * 64 + g * 16) ^ swzr));                \
      a3[m][ks] = *(const i32x4*)(Ab + (wr * 128 + (6 + m) * 16 + r) * BK +    \
                                  ((ks * 64 + g * 16) ^ swzr));                \
    }                                                                          \
    if (t_ + 2 < NT) stage(Bbw, Bg, 1, t_ + 2);                                \
    __builtin_amdgcn_s_barrier();                                              \
    asm volatile("s_waitcnt lgkmcnt(0)" ::: "memory");                         \
    __builtin_amdgcn_s_setprio(1);                                             \
    _Pragma("unroll") for (int ks = 0; ks < 2; ++ks)                           \
        _Pragma("unroll") for (int m = 0; m < 2; ++m)                          \
            _Pragma("unroll") for (int n = 0; n < 4; ++n)                      \
                acc[4 + m][n] = __builtin_amdgcn_mfma_i32_16x16x64_i8(         \
                    a2[m][ks], BFR[n][ks], acc[4 + m][n], 0, 0, 0);            \
    __builtin_amdgcn_s_setprio(0);                                             \
    __builtin_amdgcn_s_barrier();                                              \
    /* phase 3: stage (t+2).A0; vmcnt(6); barrier; read NEXT tile's B (8) */   \
    if (t_ + 2 < NT) {                                                         \
      stage(Abw, Ag, 0, t_ + 2);                                               \
      asm volatile("s_waitcnt vmcnt(6)" ::: "memory");                         \
    } else {                                                                   \
      asm volatile("s_waitcnt vmcnt(0)" ::: "memory");                         \
    }                                                                          \
    __builtin_amdgcn_s_barrier();                                              \
    if (t_ + 1 < NT) {                                                         \
      _Pragma("unroll") for (int n = 0; n < 4; ++n)                            \
          _Pragma("unroll") for (int ks = 0; ks < 2; ++ks)                     \
              BFN[n][ks] = *(const i32x4*)(BbN +                               \
                                           (wc * 64 + n * 16 + r) * BK +       \
                                           ((ks * 64 + g * 16) ^ swzr));       \
    }                                                                          \
    /* quad3 deps (a3, BFR) already drained; BFN drains at next ph0 */         \
    __builtin_amdgcn_s_setprio(1);                                             \
    _Pragma("unroll") for (int ks = 0; ks < 2; ++ks)                           \
        _Pragma("unroll") for (int m = 0; m < 2; ++m)                          \
            _Pragma("unroll") for (int n = 0; n < 4; ++n)                      \
                acc[6 + m][n] = __builtin_amdgcn_mfma_i32_16x16x64_i8(         \
                    a3[m][ks], BFR[n][ks], acc[6 + m][n], 0, 0, 0);            \
    __builtin_amdgcn_s_setprio(0);                                             \
    __builtin_amdgcn_s_barrier();                                              \
  }

  for (int tt = 0; tt < NT; tt += 2) {
    TILE_BODY(tt, 0, bfrA, bfrB)
    TILE_BODY(tt + 1, 1, bfrB, bfrA)
  }
#undef TILE_BODY

  // ---- epilogue: out = acc * xs[row]*wscale + bias[col] ----
  const float s = scale_p[0];
  const int row0 = bm * BM + wr * 128;
  const int col0 = bn * BN + wc * 64;
  float bv[4];
#pragma unroll
  for (int n = 0; n < 4; ++n) bv[n] = bias[col0 + n * 16 + r];
#pragma unroll
  for (int m = 0; m < 8; ++m) {
#pragma unroll
    for (int j = 0; j < 4; ++j) {
      const int row = row0 + m * 16 + g * 4 + j;  // C/D row = (lane>>4)*4 + reg
      const float sx = xs[row] * s;
#pragma unroll
      for (int n = 0; n < 4; ++n) {
        const int col = col0 + n * 16 + r;        // C/D col = lane & 15
        C[(size_t)row * OUT_F + col] = (float)acc[m][n][j] * sx + bv[n];
      }
    }
  }
}

// ---------------- fallback (only if ws too small) ----------------

__global__ void fallback_kernel(const float* __restrict__ x,
                                const int* __restrict__ w,
                                const float* __restrict__ scale_p,
                                const float* __restrict__ bias,
                                float* __restrict__ out) {
  size_t idx = (size_t)blockIdx.x * 256 + threadIdx.x;
  int t = (int)(idx / OUT_F);
  int o = (int)(idx % OUT_F);
  const float* xr = x + (size_t)t * IN_F;
  const int* wr = w + (size_t)o * IN_F;
  float acc = 0.f;
  for (int k = 0; k < IN_F; ++k) acc += xr[k] * (float)wr[k];
  out[idx] = acc * scale_p[0] + bias[o];
}

// ---------------- launch ----------------

extern "C" void kernel_launch(void* const* d_in, const int* in_sizes, int n_in,
                              void* d_out, int out_size, void* d_ws, size_t ws_size,
                              hipStream_t stream) {
  const float* x     = (const float*)d_in[0];
  const int*   w     = (const int*)d_in[1];
  const float* scale = (const float*)d_in[2];
  const float* bias  = (const float*)d_in[3];
  float* out = (float*)d_out;

  const size_t wq_bytes = (size_t)OUT_F * IN_F;      // 64 MB i8
  const size_t xq_bytes = (size_t)TOKENS * IN_F;     // 32 MB i8
  const size_t xs_bytes = (size_t)TOKENS * sizeof(float);

  if (ws_size >= wq_bytes + xq_bytes + xs_bytes) {
    int8_t* wq = (int8_t*)d_ws;
    int8_t* xq = (int8_t*)((char*)d_ws + wq_bytes);
    float*  xs = (float*)((char*)d_ws + wq_bytes + xq_bytes);

    convert_w_i8<<<2048, 256, 0, stream>>>(w, wq, (OUT_F * IN_F) / 16);
    convert_x_i8<<<TOKENS, 256, 0, stream>>>(x, xq, xs);

    dim3 grid((TOKENS / BM) * (OUT_F / BN));  // 32 * 64 = 2048
    ternary_gemm_i8<<<grid, 512, 0, stream>>>(xq, wq, xs, scale, bias, out);
  } else {
    size_t total = (size_t)TOKENS * OUT_F;
    fallback_kernel<<<(unsigned)(total / 256), 256, 0, stream>>>(x, w, scale, bias, out);
  }
}

// Round 7
// 626.543 us; speedup vs baseline: 2.3356x; 2.3356x over previous
//
#include <hip/hip_runtime.h>
#include <stdint.h>

#define TOKENS 8192
#define IN_F   4096
#define OUT_F  16384

#define BM 256
#define BN 256
#define BK 128                 // i8: 128 bytes per row
#define NT (IN_F / BK)         // 32 K-tiles

typedef __attribute__((ext_vector_type(4))) float f32x4;
typedef __attribute__((ext_vector_type(4))) int i32x4;

// ---------------- conversion kernels ----------------

__device__ __forceinline__ int pack4(int a, int b, int c, int d) {
  return (a & 0xff) | ((b & 0xff) << 8) | ((c & 0xff) << 16) | ((d & 0xff) << 24);
}

// w int32 {-1,0,1} -> i8, 16 elems/thread
__global__ void convert_w_i8(const int* __restrict__ w,
                             int8_t* __restrict__ wq, int n16) {
  int stride = gridDim.x * blockDim.x;
  for (int i = blockIdx.x * blockDim.x + threadIdx.x; i < n16; i += stride) {
    i32x4 o;
#pragma unroll
    for (int j = 0; j < 4; ++j) {
      i32x4 a = ((const i32x4*)w)[(size_t)i * 4 + j];
      o[j] = pack4(a.x, a.y, a.z, a.w);
    }
    ((i32x4*)wq)[i] = o;
  }
}

// x f32 -> per-token-scaled i8; one block per token (256 thr, 16 elems/thr)
__global__ void convert_x_i8(const float* __restrict__ x,
                             int8_t* __restrict__ xq,
                             float* __restrict__ xs) {
  const int t = blockIdx.x;
  const int tid = threadIdx.x;
  const float* xr = x + (size_t)t * IN_F;

  f32x4 v[4];
  float m = 0.f;
#pragma unroll
  for (int i = 0; i < 4; ++i) {
    v[i] = ((const f32x4*)xr)[tid * 4 + i];
    m = fmaxf(m, fmaxf(fmaxf(fabsf(v[i].x), fabsf(v[i].y)),
                       fmaxf(fabsf(v[i].z), fabsf(v[i].w))));
  }
#pragma unroll
  for (int off = 32; off; off >>= 1) m = fmaxf(m, __shfl_xor(m, off));
  __shared__ float sm[4];
  if ((tid & 63) == 0) sm[tid >> 6] = m;
  __syncthreads();
  m = fmaxf(fmaxf(sm[0], sm[1]), fmaxf(sm[2], sm[3]));

  const float inv = (m > 0.f) ? (127.f / m) : 0.f;
  if (tid == 0) xs[t] = m / 127.f;

  i32x4 o;
#pragma unroll
  for (int i = 0; i < 4; ++i) {
    o[i] = pack4(__float2int_rn(v[i].x * inv), __float2int_rn(v[i].y * inv),
                 __float2int_rn(v[i].z * inv), __float2int_rn(v[i].w * inv));
  }
  ((i32x4*)(xq + (size_t)t * IN_F))[tid] = o;
}

// ---------------- 256x256 8-phase i8 GEMM (16x16x64 MFMA) ----------------
// A: [TOKENS][IN_F] i8 (per-token scaled), B: [OUT_F][IN_F] i8 ternary (NT GEMM).
// C[t][o] = (sum_k Aq[t][k]*Wq[o][k]) * xs[t]*wscale + bias[o].
// R7 = R3 verbatim (measured best: GEMM 551 us, 0 conflicts, no spill).
// R5/R6 post-mortem: 2 waves/SIMD -> 256 unified regs/wave; working set
// 116 VGPR + 128 acc = 244. Any cross-tile fragment prefetch (>=16 regs)
// spills to scratch (+366 MB WRITE_SIZE, 2.5x slowdown). Phase-rebalance
// via register double-buffering is structurally impossible here.

__device__ __forceinline__ void async_lds_16B(const int8_t* g, int8_t* l) {
  __builtin_amdgcn_global_load_lds(
      reinterpret_cast<const __attribute__((address_space(1))) unsigned int*>(
          reinterpret_cast<uintptr_t>(g)),
      reinterpret_cast<__attribute__((address_space(3))) unsigned int*>(
          reinterpret_cast<uintptr_t>(l)),
      16, 0, 0);
}

__global__ __launch_bounds__(512, 2)
void ternary_gemm_i8(const int8_t* __restrict__ A,
                     const int8_t* __restrict__ B,
                     const float* __restrict__ xs,
                     const float* __restrict__ scale_p,
                     const float* __restrict__ bias,
                     float* __restrict__ C) {
  // [dbuf][A=0/B=1][256 rows * 128 B] = 128 KiB
  __shared__ __attribute__((aligned(16))) int8_t lds[2][2][BM * BK];

  const int nbn = OUT_F / BN;       // 64
  const int cpx = gridDim.x >> 3;   // 2048/8 = 256 (bijective)
  const int bid = blockIdx.x;
  const int swz = (bid & 7) * cpx + (bid >> 3);
  const int bm = swz / nbn;
  const int bn = swz % nbn;

  const int tid  = threadIdx.x;
  const int lane = tid & 63;
  const int wid  = tid >> 6;   // 0..7
  const int wr   = wid >> 2;   // 0..1 (M)
  const int wc   = wid & 3;    // 0..3 (N)

  const int r = lane & 15;          // frag row/col within 16
  const int g = lane >> 4;          // k-group 0..3
  const int swzr = (r & 7) * 16;    // read-side XOR swizzle (bytes)

  const int8_t* Ag = A + (size_t)bm * BM * IN_F;
  const int8_t* Bg = B + (size_t)bn * BN * IN_F;

  // staging: linear LDS dest (wave-uniform base + lane*16), inverse-swizzled src
  const int s_rowoff = lane >> 3;                         // 0..7
  const int s_colb   = ((lane & 7) ^ (lane >> 3)) * 16;   // pre-swizzled byte col

  auto stage = [&](int8_t* ldsTile, const int8_t* gTile, int half, int kt) {
#pragma unroll
    for (int i = 0; i < 2; ++i) {
      const int rbase = half * 128 + wid * 16 + i * 8;    // wave-uniform
      const int8_t* src =
          gTile + (size_t)(rbase + s_rowoff) * IN_F + kt * BK + s_colb;
      async_lds_16B(src, ldsTile + rbase * BK);
    }
  };

  i32x4 acc[8][4];
#pragma unroll
  for (int m = 0; m < 8; ++m)
#pragma unroll
    for (int n = 0; n < 4; ++n) acc[m][n] = i32x4{0, 0, 0, 0};

  // ---- prologue: tile0 {B0,B1,A0,A1} + tile1 {B0,B1,A0}; drain tile0 ----
  stage(&lds[0][1][0], Bg, 0, 0);
  stage(&lds[0][1][0], Bg, 1, 0);
  stage(&lds[0][0][0], Ag, 0, 0);
  stage(&lds[0][0][0], Ag, 1, 0);
  stage(&lds[1][1][0], Bg, 0, 1);
  stage(&lds[1][1][0], Bg, 1, 1);
  stage(&lds[1][0][0], Ag, 0, 1);
  asm volatile("s_waitcnt vmcnt(6)" ::: "memory");
  __builtin_amdgcn_s_barrier();

  for (int t = 0; t < NT; ++t) {
    const int cur = t & 1;
    const int8_t* Ab = &lds[cur][0][0];
    const int8_t* Bb = &lds[cur][1][0];
    int8_t* Abw = &lds[cur][0][0];
    int8_t* Bbw = &lds[cur][1][0];
    int8_t* An  = &lds[cur ^ 1][0][0];

    // ===== phase 0: read ALL B frags + A-quad0; stage (t+1).A1 =====
    i32x4 bfr[4][2];
#pragma unroll
    for (int n = 0; n < 4; ++n)
#pragma unroll
      for (int ks = 0; ks < 2; ++ks)
        bfr[n][ks] = *(const i32x4*)(Bb + (wc * 64 + n * 16 + r) * BK +
                                     ((ks * 64 + g * 16) ^ swzr));
    i32x4 a0[2][2];
#pragma unroll
    for (int m = 0; m < 2; ++m)
#pragma unroll
      for (int ks = 0; ks < 2; ++ks)
        a0[m][ks] = *(const i32x4*)(Ab + (wr * 128 + m * 16 + r) * BK +
                                    ((ks * 64 + g * 16) ^ swzr));
    if (t + 1 < NT) stage(An, Ag, 1, t + 1);
    __builtin_amdgcn_s_barrier();
    asm volatile("s_waitcnt lgkmcnt(0)" ::: "memory");
    __builtin_amdgcn_s_setprio(1);
#pragma unroll
    for (int ks = 0; ks < 2; ++ks)
#pragma unroll
      for (int m = 0; m < 2; ++m)
#pragma unroll
        for (int n = 0; n < 4; ++n)
          acc[m][n] = __builtin_amdgcn_mfma_i32_16x16x64_i8(
              a0[m][ks], bfr[n][ks], acc[m][n], 0, 0, 0);
    __builtin_amdgcn_s_setprio(0);
    __builtin_amdgcn_s_barrier();

    // ===== phase 1: read A-quad1; stage (t+2).B0 in-place =====
    i32x4 a1[2][2];
#pragma unroll
    for (int m = 0; m < 2; ++m)
#pragma unroll
      for (int ks = 0; ks < 2; ++ks)
        a1[m][ks] = *(const i32x4*)(Ab + (wr * 128 + (2 + m) * 16 + r) * BK +
                                    ((ks * 64 + g * 16) ^ swzr));
    if (t + 2 < NT) stage(Bbw, Bg, 0, t + 2);
    __builtin_amdgcn_s_barrier();
    asm volatile("s_waitcnt lgkmcnt(0)" ::: "memory");
    __builtin_amdgcn_s_setprio(1);
#pragma unroll
    for (int ks = 0; ks < 2; ++ks)
#pragma unroll
      for (int m = 0; m < 2; ++m)
#pragma unroll
        for (int n = 0; n < 4; ++n)
          acc[2 + m][n] = __builtin_amdgcn_mfma_i32_16x16x64_i8(
              a1[m][ks], bfr[n][ks], acc[2 + m][n], 0, 0, 0);
    __builtin_amdgcn_s_setprio(0);
    __builtin_amdgcn_s_barrier();

    // ===== phase 2: read A-quad2+quad3; stage (t+2).B1 in-place =====
    i32x4 a2[2][2], a3[2][2];
#pragma unroll
    for (int m = 0; m < 2; ++m)
#pragma unroll
      for (int ks = 0; ks < 2; ++ks) {
        a2[m][ks] = *(const i32x4*)(Ab + (wr * 128 + (4 + m) * 16 + r) * BK +
                                    ((ks * 64 + g * 16) ^ swzr));
        a3[m][ks] = *(const i32x4*)(Ab + (wr * 128 + (6 + m) * 16 + r) * BK +
                                    ((ks * 64 + g * 16) ^ swzr));
      }
    if (t + 2 < NT) stage(Bbw, Bg, 1, t + 2);
    __builtin_amdgcn_s_barrier();
    asm volatile("s_waitcnt lgkmcnt(0)" ::: "memory");
    __builtin_amdgcn_s_setprio(1);
#pragma unroll
    for (int ks = 0; ks < 2; ++ks)
#pragma unroll
      for (int m = 0; m < 2; ++m)
#pragma unroll
        for (int n = 0; n < 4; ++n)
          acc[4 + m][n] = __builtin_amdgcn_mfma_i32_16x16x64_i8(
              a2[m][ks], bfr[n][ks], acc[4 + m][n], 0, 0, 0);
    __builtin_amdgcn_s_setprio(0);
    __builtin_amdgcn_s_barrier();

    // ===== phase 3: stage (t+2).A0 in-place; counted vmcnt =====
    if (t + 2 < NT) {
      stage(Abw, Ag, 0, t + 2);
      asm volatile("s_waitcnt vmcnt(6)" ::: "memory");  // (t+1) fully landed
    } else {
      asm volatile("s_waitcnt vmcnt(0)" ::: "memory");
    }
    __builtin_amdgcn_s_barrier();
    asm volatile("s_waitcnt lgkmcnt(0)" ::: "memory");
    __builtin_amdgcn_s_setprio(1);
#pragma unroll
    for (int ks = 0; ks < 2; ++ks)
#pragma unroll
      for (int m = 0; m < 2; ++m)
#pragma unroll
        for (int n = 0; n < 4; ++n)
          acc[6 + m][n] = __builtin_amdgcn_mfma_i32_16x16x64_i8(
              a3[m][ks], bfr[n][ks], acc[6 + m][n], 0, 0, 0);
    __builtin_amdgcn_s_setprio(0);
    __builtin_amdgcn_s_barrier();
  }

  // ---- epilogue: out = acc * xs[row]*wscale + bias[col] ----
  const float s = scale_p[0];
  const int row0 = bm * BM + wr * 128;
  const int col0 = bn * BN + wc * 64;
  float bv[4];
#pragma unroll
  for (int n = 0; n < 4; ++n) bv[n] = bias[col0 + n * 16 + r];
#pragma unroll
  for (int m = 0; m < 8; ++m) {
#pragma unroll
    for (int j = 0; j < 4; ++j) {
      const int row = row0 + m * 16 + g * 4 + j;  // C/D row = (lane>>4)*4 + reg
      const float sx = xs[row] * s;
#pragma unroll
      for (int n = 0; n < 4; ++n) {
        const int col = col0 + n * 16 + r;        // C/D col = lane & 15
        C[(size_t)row * OUT_F + col] = (float)acc[m][n][j] * sx + bv[n];
      }
    }
  }
}

// ---------------- fallback (only if ws too small) ----------------

__global__ void fallback_kernel(const float* __restrict__ x,
                                const int* __restrict__ w,
                                const float* __restrict__ scale_p,
                                const float* __restrict__ bias,
                                float* __restrict__ out) {
  size_t idx = (size_t)blockIdx.x * 256 + threadIdx.x;
  int t = (int)(idx / OUT_F);
  int o = (int)(idx % OUT_F);
  const float* xr = x + (size_t)t * IN_F;
  const int* wr = w + (size_t)o * IN_F;
  float acc = 0.f;
  for (int k = 0; k < IN_F; ++k) acc += xr[k] * (float)wr[k];
  out[idx] = acc * scale_p[0] + bias[o];
}

// ---------------- launch ----------------

extern "C" void kernel_launch(void* const* d_in, const int* in_sizes, int n_in,
                              void* d_out, int out_size, void* d_ws, size_t ws_size,
                              hipStream_t stream) {
  const float* x     = (const float*)d_in[0];
  const int*   w     = (const int*)d_in[1];
  const float* scale = (const float*)d_in[2];
  const float* bias  = (const float*)d_in[3];
  float* out = (float*)d_out;

  const size_t wq_bytes = (size_t)OUT_F * IN_F;      // 64 MB i8
  const size_t xq_bytes = (size_t)TOKENS * IN_F;     // 32 MB i8
  const size_t xs_bytes = (size_t)TOKENS * sizeof(float);

  if (ws_size >= wq_bytes + xq_bytes + xs_bytes) {
    int8_t* wq = (int8_t*)d_ws;
    int8_t* xq = (int8_t*)((char*)d_ws + wq_bytes);
    float*  xs = (float*)((char*)d_ws + wq_bytes + xq_bytes);

    convert_w_i8<<<2048, 256, 0, stream>>>(w, wq, (OUT_F * IN_F) / 16);
    convert_x_i8<<<TOKENS, 256, 0, stream>>>(x, xq, xs);

    dim3 grid((TOKENS / BM) * (OUT_F / BN));  // 32 * 64 = 2048
    ternary_gemm_i8<<<grid, 512, 0, stream>>>(xq, wq, xs, scale, bias, out);
  } else {
    size_t total = (size_t)TOKENS * OUT_F;
    fallback_kernel<<<(unsigned)(total / 256), 256, 0, stream>>>(x, w, scale, bias, out);
  }
}

// Round 8
// 615.312 us; speedup vs baseline: 2.3782x; 1.0183x over previous
//
#include <hip/hip_runtime.h>
#include <stdint.h>

#define TOKENS 8192
#define IN_F   4096
#define OUT_F  16384

#define BM 256
#define BN 256
#define BK 128                 // i8: 128 bytes per row
#define NT (IN_F / BK)         // 32 K-tiles

typedef __attribute__((ext_vector_type(4))) float f32x4;
typedef __attribute__((ext_vector_type(4))) int i32x4;

// ---------------- conversion kernels ----------------

__device__ __forceinline__ int pack4(int a, int b, int c, int d) {
  return (a & 0xff) | ((b & 0xff) << 8) | ((c & 0xff) << 16) | ((d & 0xff) << 24);
}

// w int32 {-1,0,1} -> i8, 16 elems/thread
__global__ void convert_w_i8(const int* __restrict__ w,
                             int8_t* __restrict__ wq, int n16) {
  int stride = gridDim.x * blockDim.x;
  for (int i = blockIdx.x * blockDim.x + threadIdx.x; i < n16; i += stride) {
    i32x4 o;
#pragma unroll
    for (int j = 0; j < 4; ++j) {
      i32x4 a = ((const i32x4*)w)[(size_t)i * 4 + j];
      o[j] = pack4(a.x, a.y, a.z, a.w);
    }
    ((i32x4*)wq)[i] = o;
  }
}

// x f32 -> per-token-scaled i8; one block per token (256 thr, 16 elems/thr)
__global__ void convert_x_i8(const float* __restrict__ x,
                             int8_t* __restrict__ xq,
                             float* __restrict__ xs) {
  const int t = blockIdx.x;
  const int tid = threadIdx.x;
  const float* xr = x + (size_t)t * IN_F;

  f32x4 v[4];
  float m = 0.f;
#pragma unroll
  for (int i = 0; i < 4; ++i) {
    v[i] = ((const f32x4*)xr)[tid * 4 + i];
    m = fmaxf(m, fmaxf(fmaxf(fabsf(v[i].x), fabsf(v[i].y)),
                       fmaxf(fabsf(v[i].z), fabsf(v[i].w))));
  }
#pragma unroll
  for (int off = 32; off; off >>= 1) m = fmaxf(m, __shfl_xor(m, off));
  __shared__ float sm[4];
  if ((tid & 63) == 0) sm[tid >> 6] = m;
  __syncthreads();
  m = fmaxf(fmaxf(sm[0], sm[1]), fmaxf(sm[2], sm[3]));

  const float inv = (m > 0.f) ? (127.f / m) : 0.f;
  if (tid == 0) xs[t] = m / 127.f;

  i32x4 o;
#pragma unroll
  for (int i = 0; i < 4; ++i) {
    o[i] = pack4(__float2int_rn(v[i].x * inv), __float2int_rn(v[i].y * inv),
                 __float2int_rn(v[i].z * inv), __float2int_rn(v[i].w * inv));
  }
  ((i32x4*)(xq + (size_t)t * IN_F))[tid] = o;
}

// ---------------- 256x256 i8 GEMM (16x16x64 MFMA), pipelined windows -------
// A: [TOKENS][IN_F] i8 (per-token scaled), B: [OUT_F][IN_F] i8 ternary (NT).
// C[t][o] = (sum_k Aq[t][k]*Wq[o][k]) * xs[t]*wscale + bias[o].
// R8: same barriers/staging/vmcnt(6) invariant as R3, but each window is
//   [MFMA(quad p)] || [ds_read(quad p+1)] -> barrier
// instead of R3's [reads] -> barrier -> lgkmcnt(0) -> [MFMA]. This lets the
// LDS pipe (2313 cyc/K-tile) run concurrently with the matrix pipe
// (2612 cyc/K-tile) instead of serializing (R3: 4925 ~= measured 5166).
// Reads land in the registers the just-issued MFMAs consumed -> no extra
// liveness (R5/R6 spill wall avoided). Explicit lgkmcnt(0) dropped: reads
// are compiler-visible, hipcc inserts counted lgkm before consuming MFMA.

__device__ __forceinline__ void async_lds_16B(const int8_t* g, int8_t* l) {
  __builtin_amdgcn_global_load_lds(
      reinterpret_cast<const __attribute__((address_space(1))) unsigned int*>(
          reinterpret_cast<uintptr_t>(g)),
      reinterpret_cast<__attribute__((address_space(3))) unsigned int*>(
          reinterpret_cast<uintptr_t>(l)),
      16, 0, 0);
}

__global__ __launch_bounds__(512, 2)
void ternary_gemm_i8(const int8_t* __restrict__ A,
                     const int8_t* __restrict__ B,
                     const float* __restrict__ xs,
                     const float* __restrict__ scale_p,
                     const float* __restrict__ bias,
                     float* __restrict__ C) {
  // [dbuf][A=0/B=1][256 rows * 128 B] = 128 KiB
  __shared__ __attribute__((aligned(16))) int8_t lds[2][2][BM * BK];

  const int nbn = OUT_F / BN;       // 64
  const int cpx = gridDim.x >> 3;   // 2048/8 = 256 (bijective)
  const int bid = blockIdx.x;
  const int swz = (bid & 7) * cpx + (bid >> 3);
  const int bm = swz / nbn;
  const int bn = swz % nbn;

  const int tid  = threadIdx.x;
  const int lane = tid & 63;
  const int wid  = tid >> 6;   // 0..7
  const int wr   = wid >> 2;   // 0..1 (M)
  const int wc   = wid & 3;    // 0..3 (N)

  const int r = lane & 15;          // frag row/col within 16
  const int g = lane >> 4;          // k-group 0..3
  const int swzr = (r & 7) * 16;    // read-side XOR swizzle (bytes)

  const int8_t* Ag = A + (size_t)bm * BM * IN_F;
  const int8_t* Bg = B + (size_t)bn * BN * IN_F;

  // staging: linear LDS dest (wave-uniform base + lane*16), inverse-swizzled src
  const int s_rowoff = lane >> 3;                         // 0..7
  const int s_colb   = ((lane & 7) ^ (lane >> 3)) * 16;   // pre-swizzled byte col

  auto stage = [&](int8_t* ldsTile, const int8_t* gTile, int half, int kt) {
#pragma unroll
    for (int i = 0; i < 2; ++i) {
      const int rbase = half * 128 + wid * 16 + i * 8;    // wave-uniform
      const int8_t* src =
          gTile + (size_t)(rbase + s_rowoff) * IN_F + kt * BK + s_colb;
      async_lds_16B(src, ldsTile + rbase * BK);
    }
  };

  i32x4 acc[8][4];
#pragma unroll
  for (int m = 0; m < 8; ++m)
#pragma unroll
    for (int n = 0; n < 4; ++n) acc[m][n] = i32x4{0, 0, 0, 0};

  // ---- prologue: tile0 {B0,B1,A0,A1} + tile1 {B0,B1,A0}; drain tile0 ----
  stage(&lds[0][1][0], Bg, 0, 0);
  stage(&lds[0][1][0], Bg, 1, 0);
  stage(&lds[0][0][0], Ag, 0, 0);
  stage(&lds[0][0][0], Ag, 1, 0);
  stage(&lds[1][1][0], Bg, 0, 1);
  stage(&lds[1][1][0], Bg, 1, 1);
  stage(&lds[1][0][0], Ag, 0, 1);
  asm volatile("s_waitcnt vmcnt(6)" ::: "memory");
  __builtin_amdgcn_s_barrier();

  // pre-read tile0's B frags + A-quad0 (compiler lgkm-drains before first MFMA)
  i32x4 bfr[4][2];
  i32x4 a0[2][2], a1[2][2], a2[2][2], a3[2][2];
#pragma unroll
  for (int n = 0; n < 4; ++n)
#pragma unroll
    for (int ks = 0; ks < 2; ++ks)
      bfr[n][ks] = *(const i32x4*)(&lds[0][1][0] + (wc * 64 + n * 16 + r) * BK +
                                   ((ks * 64 + g * 16) ^ swzr));
#pragma unroll
  for (int m = 0; m < 2; ++m)
#pragma unroll
    for (int ks = 0; ks < 2; ++ks)
      a0[m][ks] = *(const i32x4*)(&lds[0][0][0] + (wr * 128 + m * 16 + r) * BK +
                                  ((ks * 64 + g * 16) ^ swzr));

  for (int t = 0; t < NT; ++t) {
    const int cur = t & 1;
    const int8_t* Ab = &lds[cur][0][0];
    int8_t* Abw = &lds[cur][0][0];
    int8_t* Bbw = &lds[cur][1][0];
    int8_t* An  = &lds[cur ^ 1][0][0];
    const int8_t* AbN = &lds[cur ^ 1][0][0];
    const int8_t* BbN = &lds[cur ^ 1][1][0];

    // ===== window 0: MFMA quad0 || read A-quad1; stage (t+1).A1 =====
    __builtin_amdgcn_s_setprio(1);
#pragma unroll
    for (int ks = 0; ks < 2; ++ks)
#pragma unroll
      for (int m = 0; m < 2; ++m)
#pragma unroll
        for (int n = 0; n < 4; ++n)
          acc[m][n] = __builtin_amdgcn_mfma_i32_16x16x64_i8(
              a0[m][ks], bfr[n][ks], acc[m][n], 0, 0, 0);
    __builtin_amdgcn_s_setprio(0);
#pragma unroll
    for (int m = 0; m < 2; ++m)
#pragma unroll
      for (int ks = 0; ks < 2; ++ks)
        a1[m][ks] = *(const i32x4*)(Ab + (wr * 128 + (2 + m) * 16 + r) * BK +
                                    ((ks * 64 + g * 16) ^ swzr));
    if (t + 1 < NT) stage(An, Ag, 1, t + 1);
    __builtin_amdgcn_s_barrier();

    // ===== window 1: MFMA quad1 || read A-quad2; stage (t+2).B0 =====
    __builtin_amdgcn_s_setprio(1);
#pragma unroll
    for (int ks = 0; ks < 2; ++ks)
#pragma unroll
      for (int m = 0; m < 2; ++m)
#pragma unroll
        for (int n = 0; n < 4; ++n)
          acc[2 + m][n] = __builtin_amdgcn_mfma_i32_16x16x64_i8(
              a1[m][ks], bfr[n][ks], acc[2 + m][n], 0, 0, 0);
    __builtin_amdgcn_s_setprio(0);
#pragma unroll
    for (int m = 0; m < 2; ++m)
#pragma unroll
      for (int ks = 0; ks < 2; ++ks)
        a2[m][ks] = *(const i32x4*)(Ab + (wr * 128 + (4 + m) * 16 + r) * BK +
                                    ((ks * 64 + g * 16) ^ swzr));
    if (t + 2 < NT) stage(Bbw, Bg, 0, t + 2);
    __builtin_amdgcn_s_barrier();

    // ===== window 2: MFMA quad2 || read A-quad3; stage (t+2).B1 =====
    __builtin_amdgcn_s_setprio(1);
#pragma unroll
    for (int ks = 0; ks < 2; ++ks)
#pragma unroll
      for (int m = 0; m < 2; ++m)
#pragma unroll
        for (int n = 0; n < 4; ++n)
          acc[4 + m][n] = __builtin_amdgcn_mfma_i32_16x16x64_i8(
              a2[m][ks], bfr[n][ks], acc[4 + m][n], 0, 0, 0);
    __builtin_amdgcn_s_setprio(0);
#pragma unroll
    for (int m = 0; m < 2; ++m)
#pragma unroll
      for (int ks = 0; ks < 2; ++ks)
        a3[m][ks] = *(const i32x4*)(Ab + (wr * 128 + (6 + m) * 16 + r) * BK +
                                    ((ks * 64 + g * 16) ^ swzr));
    if (t + 2 < NT) stage(Bbw, Bg, 1, t + 2);
    __builtin_amdgcn_s_barrier();

    // ===== window 3: MFMA quad3; stage (t+2).A0; vmcnt; read next tile's
    //                 B frags + A-quad0 from the other buffer (t+1 landed) =====
    __builtin_amdgcn_s_setprio(1);
#pragma unroll
    for (int ks = 0; ks < 2; ++ks)
#pragma unroll
      for (int m = 0; m < 2; ++m)
#pragma unroll
        for (int n = 0; n < 4; ++n)
          acc[6 + m][n] = __builtin_amdgcn_mfma_i32_16x16x64_i8(
              a3[m][ks], bfr[n][ks], acc[6 + m][n], 0, 0, 0);
    __builtin_amdgcn_s_setprio(0);
    if (t + 2 < NT) {
      stage(Abw, Ag, 0, t + 2);
      asm volatile("s_waitcnt vmcnt(6)" ::: "memory");  // (t+1) fully landed
    } else {
      asm volatile("s_waitcnt vmcnt(0)" ::: "memory");
    }
    if (t + 1 < NT) {
#pragma unroll
      for (int n = 0; n < 4; ++n)
#pragma unroll
        for (int ks = 0; ks < 2; ++ks)
          bfr[n][ks] = *(const i32x4*)(BbN + (wc * 64 + n * 16 + r) * BK +
                                       ((ks * 64 + g * 16) ^ swzr));
#pragma unroll
      for (int m = 0; m < 2; ++m)
#pragma unroll
        for (int ks = 0; ks < 2; ++ks)
          a0[m][ks] = *(const i32x4*)(AbN + (wr * 128 + m * 16 + r) * BK +
                                      ((ks * 64 + g * 16) ^ swzr));
    }
    __builtin_amdgcn_s_barrier();
  }

  // ---- epilogue: out = acc * xs[row]*wscale + bias[col] ----
  const float s = scale_p[0];
  const int row0 = bm * BM + wr * 128;
  const int col0 = bn * BN + wc * 64;
  float bv[4];
#pragma unroll
  for (int n = 0; n < 4; ++n) bv[n] = bias[col0 + n * 16 + r];
#pragma unroll
  for (int m = 0; m < 8; ++m) {
#pragma unroll
    for (int j = 0; j < 4; ++j) {
      const int row = row0 + m * 16 + g * 4 + j;  // C/D row = (lane>>4)*4 + reg
      const float sx = xs[row] * s;
#pragma unroll
      for (int n = 0; n < 4; ++n) {
        const int col = col0 + n * 16 + r;        // C/D col = lane & 15
        C[(size_t)row * OUT_F + col] = (float)acc[m][n][j] * sx + bv[n];
      }
    }
  }
}

// ---------------- fallback (only if ws too small) ----------------

__global__ void fallback_kernel(const float* __restrict__ x,
                                const int* __restrict__ w,
                                const float* __restrict__ scale_p,
                                const float* __restrict__ bias,
                                float* __restrict__ out) {
  size_t idx = (size_t)blockIdx.x * 256 + threadIdx.x;
  int t = (int)(idx / OUT_F);
  int o = (int)(idx % OUT_F);
  const float* xr = x + (size_t)t * IN_F;
  const int* wr = w + (size_t)o * IN_F;
  float acc = 0.f;
  for (int k = 0; k < IN_F; ++k) acc += xr[k] * (float)wr[k];
  out[idx] = acc * scale_p[0] + bias[o];
}

// ---------------- launch ----------------

extern "C" void kernel_launch(void* const* d_in, const int* in_sizes, int n_in,
                              void* d_out, int out_size, void* d_ws, size_t ws_size,
                              hipStream_t stream) {
  const float* x     = (const float*)d_in[0];
  const int*   w     = (const int*)d_in[1];
  const float* scale = (const float*)d_in[2];
  const float* bias  = (const float*)d_in[3];
  float* out = (float*)d_out;

  const size_t wq_bytes = (size_t)OUT_F * IN_F;      // 64 MB i8
  const size_t xq_bytes = (size_t)TOKENS * IN_F;     // 32 MB i8
  const size_t xs_bytes = (size_t)TOKENS * sizeof(float);

  if (ws_size >= wq_bytes + xq_bytes + xs_bytes) {
    int8_t* wq = (int8_t*)d_ws;
    int8_t* xq = (int8_t*)((char*)d_ws + wq_bytes);
    float*  xs = (float*)((char*)d_ws + wq_bytes + xq_bytes);

    convert_w_i8<<<2048, 256, 0, stream>>>(w, wq, (OUT_F * IN_F) / 16);
    convert_x_i8<<<TOKENS, 256, 0, stream>>>(x, xq, xs);

    dim3 grid((TOKENS / BM) * (OUT_F / BN));  // 32 * 64 = 2048
    ternary_gemm_i8<<<grid, 512, 0, stream>>>(xq, wq, xs, scale, bias, out);
  } else {
    size_t total = (size_t)TOKENS * OUT_F;
    fallback_kernel<<<(unsigned)(total / 256), 256, 0, stream>>>(x, w, scale, bias, out);
  }
}